// Round 5
// baseline (187.622 us; speedup 1.0000x reference)
//
#include <hip/hip_runtime.h>

#define BATCH 8
#define NN 10000      // nodes per graph (N)
#define STB 128       // 2 waves: table 40K + 2 private acc 80K + mark 10K = 130KB

typedef _Float16 h2 __attribute__((ext_vector_type(2)));
typedef _Float16 h4 __attribute__((ext_vector_type(4)));

// Packed 2xf16 LDS atomic add -- loser-lane fallback only.
__device__ __forceinline__ void lds_pk_add(h2* p, h2 v) {
    __builtin_amdgcn_ds_atomic_fadd_v2f16(
        (__attribute__((address_space(3))) h2*)p, v);
}

// prep: fx2[bp*N + t] = { tanh(values[2bp*N+t]), tanh(values[(2bp+1)*N+t]) }
__global__ __launch_bounds__(256) void prep_kernel(
        const float* __restrict__ values, h2* __restrict__ fx2, int N)
{
    int i = blockIdx.x * 256 + threadIdx.x;
    if (i >= 4 * N) return;
    int bp = i / N, t = i - bp * N;
    float a = values[(long)(2 * bp) * N + t];
    float b = values[(long)(2 * bp + 1) * N + t];
    h2 f = { (_Float16)tanhf(a), (_Float16)tanhf(b) };
    fx2[i] = f;
}

// Scatter, all-LDS version:
//  - gather table staged in LDS (40KB): ds_read_b32 replaces the divergent
//    VMEM gather that bound rounds 0-4 (~3.5 cyc/lane TA law -> ~0.2 cyc/lane)
//  - 2 waves, each a PRIVATE acc copy (no inter-wave races)
//  - shared volatile u8 mark[]: all lanes write tid, read back; survivor is
//    the exclusive winner -> batched non-atomic RMW; losers (rare) use ds
//    atomic AFTER the batched writes (same-wave DS ops are in-order).
//  - same-lane duplicate addresses within the 8-batch are demoted to the
//    loser path (28 VALU compares) so batched reads/writes stay hazard-free.
__global__ __launch_bounds__(STB) void scatter_kernel(
        const h2* __restrict__ g2,       // [4*N] packed gather values
        const float* __restrict__ w,     // [E]
        const int* __restrict__ idx,     // [2,E]
        h2* __restrict__ partial,
        int E, int N, int chunk, long goff, long soff)
{
    __shared__ __align__(16) char smem[130000];
    h2* acc   = (h2*)smem;                                   // 2 x [NN] h2
    h2* table = (h2*)(smem + 80000);                         // [NN] h2
    volatile unsigned char* mark = (unsigned char*)(smem + 120000);  // [NN]

    const int tid = threadIdx.x;
    const int wid = tid >> 6;
    const int k = blockIdx.x, bp = blockIdx.y;
    const h2* __restrict__ gb = g2 + (long)bp * N;
    h2* ac = acc + wid * NN;

    // zero 2 acc copies (80KB) and stage gather table (40KB, L2-broadcast)
    int4* az = (int4*)smem;
    for (int i = tid; i < 5000; i += STB) az[i] = make_int4(0, 0, 0, 0);
    int4* tz = (int4*)(smem + 80000);
    const int4* gsrc = (const int4*)gb;
    for (int i = tid; i < 2500; i += STB) tz[i] = gsrc[i];
    __syncthreads();

    long e0 = (long)k * chunk, e1 = e0 + chunk;
    if (e0 > E) e0 = E;
    if (e1 > E) e1 = E;
    long n = e1 - e0;
    long nv8 = n >> 3;                     // 8-edge groups
    const int4*   g4p = (const int4*)(idx + goff + e0);
    const int4*   s4p = (const int4*)(idx + soff + e0);
    const float4* w4p = (const float4*)(w + e0);

    const unsigned char my = (unsigned char)tid;

    for (long v = tid; v < nv8; v += STB) {
        int4 giA = g4p[2 * v], giB = g4p[2 * v + 1];
        int4 siA = s4p[2 * v], siB = s4p[2 * v + 1];
        float4 wvA = w4p[2 * v], wvB = w4p[2 * v + 1];
        int s0 = siA.x, s1 = siA.y, s2 = siA.z, s3 = siA.w;
        int s4 = siB.x, s5 = siB.y, s6 = siB.z, s7 = siB.w;
        // phase 1: 8 independent LDS gathers
        h2 f0 = table[giA.x], f1 = table[giA.y], f2 = table[giA.z], f3 = table[giA.w];
        h2 f4 = table[giB.x], f5 = table[giB.y], f6 = table[giB.z], f7 = table[giB.w];
        h2 q0 = { (_Float16)wvA.x, (_Float16)wvA.x };
        h2 q1 = { (_Float16)wvA.y, (_Float16)wvA.y };
        h2 q2 = { (_Float16)wvA.z, (_Float16)wvA.z };
        h2 q3 = { (_Float16)wvA.w, (_Float16)wvA.w };
        h2 q4 = { (_Float16)wvB.x, (_Float16)wvB.x };
        h2 q5 = { (_Float16)wvB.y, (_Float16)wvB.y };
        h2 q6 = { (_Float16)wvB.z, (_Float16)wvB.z };
        h2 q7 = { (_Float16)wvB.w, (_Float16)wvB.w };
        h2 v0 = q0 * f0, v1 = q1 * f1, v2 = q2 * f2, v3 = q3 * f3;
        h2 v4 = q4 * f4, v5 = q5 * f5, v6 = q6 * f6, v7 = q7 * f7;
        // phase 2: 8 mark writes, then 8 mark reads (volatile keeps order)
        mark[s0] = my; mark[s1] = my; mark[s2] = my; mark[s3] = my;
        mark[s4] = my; mark[s5] = my; mark[s6] = my; mark[s7] = my;
        bool n0 = (mark[s0] == my), n1 = (mark[s1] == my);
        bool n2 = (mark[s2] == my), n3 = (mark[s3] == my);
        bool n4 = (mark[s4] == my), n5 = (mark[s5] == my);
        bool n6 = (mark[s6] == my), n7 = (mark[s7] == my);
        // same-lane duplicate demotion (keeps winner addresses distinct)
        bool d1 = (s1 == s0);
        bool d2 = (s2 == s0) | (s2 == s1);
        bool d3 = (s3 == s0) | (s3 == s1) | (s3 == s2);
        bool d4 = (s4 == s0) | (s4 == s1) | (s4 == s2) | (s4 == s3);
        bool d5 = (s5 == s0) | (s5 == s1) | (s5 == s2) | (s5 == s3) | (s5 == s4);
        bool d6 = (s6 == s0) | (s6 == s1) | (s6 == s2) | (s6 == s3) | (s6 == s4) | (s6 == s5);
        bool d7 = (s7 == s0) | (s7 == s1) | (s7 == s2) | (s7 == s3) | (s7 == s4) | (s7 == s5) | (s7 == s6);
        bool W0 = n0,        W1 = n1 && !d1, W2 = n2 && !d2, W3 = n3 && !d3;
        bool W4 = n4 && !d4, W5 = n5 && !d5, W6 = n6 && !d6, W7 = n7 && !d7;
        // phase 3: 8 independent acc reads (losers' values discarded)
        h2 r0 = ac[s0], r1 = ac[s1], r2 = ac[s2], r3 = ac[s3];
        h2 r4 = ac[s4], r5 = ac[s5], r6 = ac[s6], r7 = ac[s7];
        // phase 4: winner writes (pairwise-distinct addresses)
        if (W0) ac[s0] = r0 + v0;
        if (W1) ac[s1] = r1 + v1;
        if (W2) ac[s2] = r2 + v2;
        if (W3) ac[s3] = r3 + v3;
        if (W4) ac[s4] = r4 + v4;
        if (W5) ac[s5] = r5 + v5;
        if (W6) ac[s6] = r6 + v6;
        if (W7) ac[s7] = r7 + v7;
        // phase 5: loser atomics -- AFTER the writes (same-wave DS in-order)
        if (!W0) lds_pk_add(&ac[s0], v0);
        if (!W1) lds_pk_add(&ac[s1], v1);
        if (!W2) lds_pk_add(&ac[s2], v2);
        if (!W3) lds_pk_add(&ac[s3], v3);
        if (!W4) lds_pk_add(&ac[s4], v4);
        if (!W5) lds_pk_add(&ac[s5], v5);
        if (!W6) lds_pk_add(&ac[s6], v6);
        if (!W7) lds_pk_add(&ac[s7], v7);
    }
    for (long e = (nv8 << 3) + tid; e < n; e += STB) {
        int gi = idx[goff + e0 + e], si = idx[soff + e0 + e];
        _Float16 wf = (_Float16)w[e0 + e];
        h2 wb = { wf, wf };
        h2 val = wb * table[gi];
        mark[si] = my;
        bool win = (mark[si] == my);
        if (win) ac[si] = ac[si] + val;
        else     lds_pk_add(&ac[si], val);
    }
    __syncthreads();

    // fold the 2 copies, write partial row
    h4* a0 = (h4*)(smem);
    h4* a1 = (h4*)(smem + 40000);
    h4* pz = (h4*)(partial + ((long)k * 4 + bp) * N);
    for (int i = tid; i < NN / 2; i += STB) {
        h4 s = a0[i] + a1[i];
        pz[i] = s;
    }
}

// ---------------- reduce 1 (flat): pred, err, err2 ----------------
__global__ __launch_bounds__(256) void reduce1_kernel(
        const h2* __restrict__ partial,
        const float* __restrict__ values,
        float* __restrict__ pred, float* __restrict__ err,
        h2* __restrict__ err2, int N, int K)
{
    int t = blockIdx.x * 256 + threadIdx.x;
    int bp = blockIdx.y;
    if (t >= N) return;
    float sx = 0.f, sy = 0.f;
    const h2* __restrict__ p = partial + (long)bp * N + t;
#pragma unroll 8
    for (int kk = 0; kk < K; ++kk) {
        h2 v = p[(long)kk * 4 * N];
        sx += (float)v.x; sy += (float)v.y;
    }
    long j0 = (long)(2 * bp) * N + t, j1 = j0 + N;
    float v0 = values[j0], v1 = values[j1];
    float e0 = v0 - sx, e1 = v1 - sy;
    pred[j0] = sx; pred[j1] = sy;
    err[j0] = e0;  err[j1] = e1;
    h2 pk = { (_Float16)e0, (_Float16)e1 };
    err2[(long)bp * N + t] = pk;
}

// ---------------- reduce 2 (flat): dx = err - (1 - tanh^2(x)) * aggr ----------------
__global__ __launch_bounds__(256) void reduce2_kernel(
        const h2* __restrict__ partial,
        const float* __restrict__ values,
        const float* __restrict__ err,
        float* __restrict__ dx, int N, int K)
{
    int t = blockIdx.x * 256 + threadIdx.x;
    int bp = blockIdx.y;
    if (t >= N) return;
    float sx = 0.f, sy = 0.f;
    const h2* __restrict__ p = partial + (long)bp * N + t;
#pragma unroll 8
    for (int kk = 0; kk < K; ++kk) {
        h2 v = p[(long)kk * 4 * N];
        sx += (float)v.x; sy += (float)v.y;
    }
    long j0 = (long)(2 * bp) * N + t, j1 = j0 + N;
    float v0 = values[j0], v1 = values[j1];
    float f0 = tanhf(v0), f1 = tanhf(v1);
    dx[j0] = err[j0] - (1.0f - f0 * f0) * sx;
    dx[j1] = err[j1] - (1.0f - f1 * f1) * sy;
}

extern "C" void kernel_launch(void* const* d_in, const int* in_sizes, int n_in,
                              void* d_out, int out_size, void* d_ws, size_t ws_size,
                              hipStream_t stream) {
    const float* values  = (const float*)d_in[0];   // [B*N]
    const float* weights = (const float*)d_in[1];   // [E]
    const int*   edge_ix = (const int*)d_in[2];     // [2, E]

    const int BN = in_sizes[0];        // 80000
    const int E  = in_sizes[1];        // 2,000,000
    const int N  = BN / BATCH;         // 10000

    float* out  = (float*)d_out;       // [3, B*N]
    float* pred = out;
    float* err  = out + BN;
    float* dx   = out + 2 * BN;

    // workspace: fx2 [4N] h2 | err2 [4N] h2 | partial [K*4][N] h2
    auto align16 = [](size_t x) { return (x + 15) & ~(size_t)15; };
    char* ws = (char*)d_ws;
    h2* fx2 = (h2*)ws;
    size_t off = align16((size_t)4 * N * sizeof(h2));
    h2* err2 = (h2*)(ws + off);
    off += align16((size_t)4 * N * sizeof(h2));
    // K=64 -> 256 scatter blocks = 1/CU (130KB LDS forces 1/CU anyway)
    int K = 64;
    while (K > 16 && off + (size_t)K * 4 * N * sizeof(h2) > ws_size) K >>= 1;
    h2* partial = (h2*)(ws + off);

    int chunk = (((E + K - 1) / K) + 7) & ~7;   // multiple of 8
    int Kused = (E + chunk - 1) / chunk;

    dim3 sgrid(Kused, 4);                 // 4 batch-pairs
    dim3 rgrid((N + 255) / 256, 4);       // flat reduce: 1 thread per (node,bp)

    prep_kernel<<<(4 * N + 255) / 256, 256, 0, stream>>>(values, fx2, N);
    scatter_kernel<<<sgrid, STB, 0, stream>>>(fx2, weights, edge_ix, partial,
                                              E, N, chunk, 0L, (long)E);
    reduce1_kernel<<<rgrid, 256, 0, stream>>>(partial, values, pred, err,
                                              err2, N, Kused);
    scatter_kernel<<<sgrid, STB, 0, stream>>>(err2, weights, edge_ix, partial,
                                              E, N, chunk, (long)E, 0L);
    reduce2_kernel<<<rgrid, 256, 0, stream>>>(partial, values, err, dx,
                                              N, Kused);
}

// Round 6
// 151.961 us; speedup vs baseline: 1.2347x; 1.2347x over previous
//
#include <hip/hip_runtime.h>

#define BATCH 8
#define NN 10000      // nodes per graph (N)
#define STB 128       // 2 waves; LDS: 2x40K private acc + 40K table + 20K mark = 140KB

typedef _Float16 h2 __attribute__((ext_vector_type(2)));
typedef _Float16 h4 __attribute__((ext_vector_type(4)));

// Packed 2xf16 LDS atomic add -- loser-lane fallback only.
__device__ __forceinline__ void lds_pk_add(h2* p, h2 v) {
    __builtin_amdgcn_ds_atomic_fadd_v2f16(
        (__attribute__((address_space(3))) h2*)p, v);
}

// LDS byte offset of a __shared__ object (as3 ptrtoint).
__device__ __forceinline__ unsigned lds_addr(const void* p) {
    return (unsigned)(unsigned long long)
        ((const __attribute__((address_space(3))) void*)p);
}

// Raw DS mark ops: no volatile per-op drains; ordering handled by ONE
// s_waitcnt lgkmcnt(0) + sched_barrier per group (rule #18).
__device__ __forceinline__ void mark_w(unsigned a, unsigned d) {
    asm volatile("ds_write_b16 %0, %1" :: "v"(a), "v"(d));
}
__device__ __forceinline__ unsigned mark_r(unsigned a) {
    unsigned r;
    asm volatile("ds_read_u16 %0, %1" : "=v"(r) : "v"(a));
    return r;
}

// prep: fx2[bp*N + t] = { tanh(values[2bp*N+t]), tanh(values[(2bp+1)*N+t]) }
__global__ __launch_bounds__(256) void prep_kernel(
        const float* __restrict__ values, h2* __restrict__ fx2, int N)
{
    int i = blockIdx.x * 256 + threadIdx.x;
    if (i >= 4 * N) return;
    int bp = i / N, t = i - bp * N;
    float a = values[(long)(2 * bp) * N + t];
    float b = values[(long)(2 * bp + 1) * N + t];
    h2 f = { (_Float16)tanhf(a), (_Float16)tanhf(b) };
    fx2[i] = f;
}

// Scatter, all-LDS, drain-free marks:
//  - gather table in LDS (ds_read_b32, no divergent VMEM)
//  - 2 waves, PRIVATE acc copies (no inter-wave races)
//  - u16 mark tags (tid<<4)|slot: last-writer survives; writes issued in
//    DESCENDING slot order so the earliest duplicate slot of a lane is the
//    winner -> its batched non-atomic RMW precedes later dup atomics in
//    wave program order (DS executes in order within a wave). Losers
//    (cross-lane/cross-slot collisions) use ds_pk_add on their own copy.
__global__ __launch_bounds__(STB, 1) void scatter_kernel(
        const h2* __restrict__ g2,       // [4*N] packed gather values
        const float* __restrict__ w,     // [E]
        const int* __restrict__ idx,     // [2,E]
        h2* __restrict__ partial,
        int E, int N, int chunk, long goff, long soff)
{
    __shared__ __align__(16) char smem[140000];
    h2* acc   = (h2*)smem;                           // 2 x [NN] h2
    h2* table = (h2*)(smem + 80000);                 // [NN] h2
    unsigned short* mark = (unsigned short*)(smem + 120000);  // [NN] u16

    const int tid = threadIdx.x;
    const int wid = tid >> 6;
    const int k = blockIdx.x, bp = blockIdx.y;
    const h2* __restrict__ gb = g2 + (long)bp * N;
    h2* ac = acc + wid * NN;
    const unsigned markBase = lds_addr(mark);

    // zero 2 acc copies (80KB) and stage gather table (40KB, L2-broadcast)
    int4* az = (int4*)smem;
    for (int i = tid; i < 5000; i += STB) az[i] = make_int4(0, 0, 0, 0);
    int4* tz = (int4*)(smem + 80000);
    const int4* gsrc = (const int4*)gb;
    for (int i = tid; i < 2500; i += STB) tz[i] = gsrc[i];
    __syncthreads();

    long e0 = (long)k * chunk, e1 = e0 + chunk;
    if (e0 > E) e0 = E;
    if (e1 > E) e1 = E;
    long n = e1 - e0;
    long nv16 = n >> 4;                    // 16-edge groups
    const int4*   g4p = (const int4*)(idx + goff + e0);
    const int4*   s4p = (const int4*)(idx + soff + e0);
    const float4* w4p = (const float4*)(w + e0);

    for (long v = tid; v < nv16; v += STB) {
        int4 GA = g4p[4*v], GB = g4p[4*v+1], GC = g4p[4*v+2], GD = g4p[4*v+3];
        int4 SA = s4p[4*v], SB = s4p[4*v+1], SC = s4p[4*v+2], SD = s4p[4*v+3];
        float4 WA = w4p[4*v], WB = w4p[4*v+1], WC = w4p[4*v+2], WD = w4p[4*v+3];
        int gi[16] = { GA.x,GA.y,GA.z,GA.w, GB.x,GB.y,GB.z,GB.w,
                       GC.x,GC.y,GC.z,GC.w, GD.x,GD.y,GD.z,GD.w };
        int si[16] = { SA.x,SA.y,SA.z,SA.w, SB.x,SB.y,SB.z,SB.w,
                       SC.x,SC.y,SC.z,SC.w, SD.x,SD.y,SD.z,SD.w };
        float wf[16] = { WA.x,WA.y,WA.z,WA.w, WB.x,WB.y,WB.z,WB.w,
                         WC.x,WC.y,WC.z,WC.w, WD.x,WD.y,WD.z,WD.w };
        // phase 1: 16 independent LDS table gathers + weight products
        h2 val[16];
#pragma unroll
        for (int j = 0; j < 16; ++j) {
            h2 q = { (_Float16)wf[j], (_Float16)wf[j] };
            val[j] = q * table[gi[j]];
        }
        unsigned ma[16];
#pragma unroll
        for (int j = 0; j < 16; ++j) ma[j] = markBase + 2u * (unsigned)si[j];
        // phase 2a: 16 mark writes, descending slot order
#pragma unroll
        for (int j = 15; j >= 0; --j)
            mark_w(ma[j], (unsigned)((tid << 4) | j));
        // phase 2b: 16 mark reads, then ONE drain
        unsigned rr[16];
#pragma unroll
        for (int j = 0; j < 16; ++j) rr[j] = mark_r(ma[j]);
        asm volatile("s_waitcnt lgkmcnt(0)" ::: "memory");
        __builtin_amdgcn_sched_barrier(0);
        // phase 3: 16 independent acc reads
        h2 old[16];
#pragma unroll
        for (int j = 0; j < 16; ++j) old[j] = ac[si[j]];
        bool W[16];
#pragma unroll
        for (int j = 0; j < 16; ++j)
            W[j] = (rr[j] == (unsigned)((tid << 4) | j));
        // phase 4: winner stores (pairwise-distinct addresses per wave)
#pragma unroll
        for (int j = 0; j < 16; ++j)
            if (W[j]) ac[si[j]] = old[j] + val[j];
        // phase 5: loser atomics -- after the stores (same-wave DS in-order)
#pragma unroll
        for (int j = 0; j < 16; ++j)
            if (!W[j]) lds_pk_add(&ac[si[j]], val[j]);
    }
    // tail: rare (chunk is a multiple of 16); plain atomic path
    for (long e = (nv16 << 4) + tid; e < n; e += STB) {
        int gi = idx[goff + e0 + e], si = idx[soff + e0 + e];
        _Float16 wf = (_Float16)w[e0 + e];
        h2 wb = { wf, wf };
        lds_pk_add(&ac[si], wb * table[gi]);
    }
    __syncthreads();

    // fold the 2 copies, write partial row
    h4* a0 = (h4*)(smem);
    h4* a1 = (h4*)(smem + 40000);
    h4* pz = (h4*)(partial + ((long)k * 4 + bp) * N);
    for (int i = tid; i < NN / 2; i += STB) {
        h4 s = a0[i] + a1[i];
        pz[i] = s;
    }
}

// ---------------- reduce 1 (flat): pred, err, err2 ----------------
__global__ __launch_bounds__(256) void reduce1_kernel(
        const h2* __restrict__ partial,
        const float* __restrict__ values,
        float* __restrict__ pred, float* __restrict__ err,
        h2* __restrict__ err2, int N, int K)
{
    int t = blockIdx.x * 256 + threadIdx.x;
    int bp = blockIdx.y;
    if (t >= N) return;
    float sx = 0.f, sy = 0.f;
    const h2* __restrict__ p = partial + (long)bp * N + t;
#pragma unroll 8
    for (int kk = 0; kk < K; ++kk) {
        h2 v = p[(long)kk * 4 * N];
        sx += (float)v.x; sy += (float)v.y;
    }
    long j0 = (long)(2 * bp) * N + t, j1 = j0 + N;
    float v0 = values[j0], v1 = values[j1];
    float e0 = v0 - sx, e1 = v1 - sy;
    pred[j0] = sx; pred[j1] = sy;
    err[j0] = e0;  err[j1] = e1;
    h2 pk = { (_Float16)e0, (_Float16)e1 };
    err2[(long)bp * N + t] = pk;
}

// ---------------- reduce 2 (flat): dx = err - (1 - tanh^2(x)) * aggr ----------------
__global__ __launch_bounds__(256) void reduce2_kernel(
        const h2* __restrict__ partial,
        const float* __restrict__ values,
        const float* __restrict__ err,
        float* __restrict__ dx, int N, int K)
{
    int t = blockIdx.x * 256 + threadIdx.x;
    int bp = blockIdx.y;
    if (t >= N) return;
    float sx = 0.f, sy = 0.f;
    const h2* __restrict__ p = partial + (long)bp * N + t;
#pragma unroll 8
    for (int kk = 0; kk < K; ++kk) {
        h2 v = p[(long)kk * 4 * N];
        sx += (float)v.x; sy += (float)v.y;
    }
    long j0 = (long)(2 * bp) * N + t, j1 = j0 + N;
    float v0 = values[j0], v1 = values[j1];
    float f0 = tanhf(v0), f1 = tanhf(v1);
    dx[j0] = err[j0] - (1.0f - f0 * f0) * sx;
    dx[j1] = err[j1] - (1.0f - f1 * f1) * sy;
}

extern "C" void kernel_launch(void* const* d_in, const int* in_sizes, int n_in,
                              void* d_out, int out_size, void* d_ws, size_t ws_size,
                              hipStream_t stream) {
    const float* values  = (const float*)d_in[0];   // [B*N]
    const float* weights = (const float*)d_in[1];   // [E]
    const int*   edge_ix = (const int*)d_in[2];     // [2, E]

    const int BN = in_sizes[0];        // 80000
    const int E  = in_sizes[1];        // 2,000,000
    const int N  = BN / BATCH;         // 10000

    float* out  = (float*)d_out;       // [3, B*N]
    float* pred = out;
    float* err  = out + BN;
    float* dx   = out + 2 * BN;

    // workspace: fx2 [4N] h2 | err2 [4N] h2 | partial [K*4][N] h2
    auto align16 = [](size_t x) { return (x + 15) & ~(size_t)15; };
    char* ws = (char*)d_ws;
    h2* fx2 = (h2*)ws;
    size_t off = align16((size_t)4 * N * sizeof(h2));
    h2* err2 = (h2*)(ws + off);
    off += align16((size_t)4 * N * sizeof(h2));
    // K=64 -> 256 scatter blocks = 1/CU (140KB LDS forces 1/CU anyway)
    int K = 64;
    while (K > 16 && off + (size_t)K * 4 * N * sizeof(h2) > ws_size) K >>= 1;
    h2* partial = (h2*)(ws + off);

    int chunk = (((E + K - 1) / K) + 15) & ~15;   // multiple of 16
    int Kused = (E + chunk - 1) / chunk;

    dim3 sgrid(Kused, 4);                 // 4 batch-pairs
    dim3 rgrid((N + 255) / 256, 4);       // flat reduce: 1 thread per (node,bp)

    prep_kernel<<<(4 * N + 255) / 256, 256, 0, stream>>>(values, fx2, N);
    scatter_kernel<<<sgrid, STB, 0, stream>>>(fx2, weights, edge_ix, partial,
                                              E, N, chunk, 0L, (long)E);
    reduce1_kernel<<<rgrid, 256, 0, stream>>>(partial, values, pred, err,
                                              err2, N, Kused);
    scatter_kernel<<<sgrid, STB, 0, stream>>>(err2, weights, edge_ix, partial,
                                              E, N, chunk, (long)E, 0L);
    reduce2_kernel<<<rgrid, 256, 0, stream>>>(partial, values, err, dx,
                                              N, Kused);
}